// Round 1
// baseline (1044.777 us; speedup 1.0000x reference)
//
#include <hip/hip_runtime.h>
#include <hip/hip_bf16.h>

#define FIN 512
#define HD 32

// ---------------- degree / normalization ----------------
__global__ __launch_bounds__(256) void k_deg_init(int* deg, int N) {
  int i = blockIdx.x * 256 + threadIdx.x;
  if (i < N) deg[i] = 1;  // self-loop
}

__global__ __launch_bounds__(256) void k_deg_count(const int* __restrict__ dst, int* deg, int E) {
  int i = blockIdx.x * 256 + threadIdx.x;
  int stride = gridDim.x * 256;
  for (; i < E; i += stride) atomicAdd(&deg[dst[i]], 1);
}

__global__ __launch_bounds__(256) void k_dis(const int* __restrict__ deg, float* dis, int N) {
  int i = blockIdx.x * 256 + threadIdx.x;
  if (i < N) dis[i] = rsqrtf((float)deg[i]);
}

__global__ __launch_bounds__(256) void k_norm(const int* __restrict__ src, const int* __restrict__ dst,
                                              const float* __restrict__ dis, float* __restrict__ nrm, int E) {
  int i = blockIdx.x * 256 + threadIdx.x;
  int stride = gridDim.x * 256;
  for (; i < E; i += stride) nrm[i] = dis[src[i]] * dis[dst[i]];
}

// ---------------- mm1: h1 = x @ W1  ([N,512]@[512,32]) ----------------
// Block = 256 threads = 4 waves = 8 half-waves; each half-wave owns one row,
// lane-in-half = output column. W1 (64KB) + 8 x-rows (16KB) staged in LDS.
__global__ __launch_bounds__(256) void k_mm1(const float* __restrict__ x, const float* __restrict__ W1,
                                             float* __restrict__ h1, int N) {
  __shared__ float w[FIN * HD];   // 64 KB
  __shared__ float xs[8][FIN];    // 16 KB
  const int t = threadIdx.x;

  // stage W1 once per block (coalesced float4)
  for (int i = t; i < FIN * HD / 4; i += 256)
    ((float4*)w)[i] = ((const float4*)W1)[i];
  __syncthreads();

  const int wave = t >> 6;
  const int lane = t & 63;
  const int half = lane >> 5;   // which of the 2 rows this wave handles
  const int c    = lane & 31;   // output column

  for (int base = blockIdx.x * 8; base < N; base += gridDim.x * 8) {
    __syncthreads();  // protect xs from previous iteration's readers
    int nrows = N - base; if (nrows > 8) nrows = 8;
    // cooperative stage of rows [base, base+nrows): contiguous -> perfectly coalesced
    for (int i = t; i < nrows * (FIN / 4); i += 256)
      ((float4*)&xs[0][0])[i] = ((const float4*)&x[(size_t)base * FIN])[i];
    __syncthreads();

    int row = base + wave * 2 + half;
    if (row < N) {
      const float* xr = xs[wave * 2 + half];
      float a0 = 0.f, a1 = 0.f, a2 = 0.f, a3 = 0.f;
#pragma unroll 4
      for (int k = 0; k < FIN; k += 4) {
        float4 xv = *(const float4*)&xr[k];        // LDS b128, broadcast within half-wave
        a0 += xv.x * w[(k + 0) * HD + c];          // stride-1 across lanes: conflict-free
        a1 += xv.y * w[(k + 1) * HD + c];
        a2 += xv.z * w[(k + 2) * HD + c];
        a3 += xv.w * w[(k + 3) * HD + c];
      }
      h1[(size_t)row * HD + c] = (a0 + a1) + (a2 + a3);
    }
  }
}

// ---------------- self-loop init: agg[i,c] = h[i,c] * dis[i]^2 ----------------
__global__ __launch_bounds__(256) void k_selfinit(const float* __restrict__ h, const float* __restrict__ dis,
                                                  float* __restrict__ agg, int N) {
  long long i = (long long)blockIdx.x * 256 + threadIdx.x;
  long long total = (long long)N * HD;
  long long stride = (long long)gridDim.x * 256;
  for (; i < total; i += stride) {
    int row = (int)(i >> 5);
    float d = dis[row];
    agg[i] = h[i] * d * d;
  }
}

// ---------------- push scatter: agg[dst] += h[src] * norm ----------------
__global__ __launch_bounds__(256) void k_scatter(const int* __restrict__ src, const int* __restrict__ dst,
                                                 const float* __restrict__ nrm, const float* __restrict__ h,
                                                 float* __restrict__ agg, long long Etot) {
  long long i = (long long)blockIdx.x * 256 + threadIdx.x;
  long long stride = (long long)gridDim.x * 256;
  for (; i < Etot; i += stride) {
    int e = (int)(i >> 5);
    int c = (int)(i & 31);
    int s = src[e], d = dst[e];
    float v = h[(size_t)s * HD + c] * nrm[e];
    unsafeAtomicAdd(&agg[(size_t)d * HD + c], v);   // HW global_atomic_add_f32
  }
}

// ---------------- mm2 fused: t=relu(agg1+b1); h2=t@W2; out_init=h2*dis^2 ----------------
__global__ __launch_bounds__(256) void k_mm2(const float* __restrict__ agg1, const float* __restrict__ b1,
                                             const float* __restrict__ W2, const float* __restrict__ dis,
                                             float* __restrict__ h2, float* __restrict__ out, int N) {
  __shared__ float w[HD * HD];
  __shared__ float bb[HD];
  int t = threadIdx.x;
  if (t < HD) bb[t] = b1[t];
  for (int i = t; i < HD * HD; i += 256) w[i] = W2[i];
  __syncthreads();

  int lane = t & 63, c = lane & 31;
  int halfId = (blockIdx.x * 4 + (t >> 6)) * 2 + (lane >> 5);  // global half-wave id = row
  int stride = gridDim.x * 8;
  for (int row = halfId; row < N; row += stride) {
    float tv = fmaxf(agg1[(size_t)row * HD + c] + bb[c], 0.f);
    float acc = 0.f;
#pragma unroll
    for (int k = 0; k < HD; ++k) {
      float tk = __shfl(tv, k, 32);   // broadcast t[k] within half-wave
      acc += tk * w[k * HD + c];
    }
    float d = dis[row];
    h2[(size_t)row * HD + c]  = acc;
    out[(size_t)row * HD + c] = acc * d * d;   // self-loop init of layer-2 aggregation
  }
}

// ---------------- final: out = log_softmax(out + b2) ----------------
__global__ __launch_bounds__(256) void k_lsm(float* __restrict__ out, const float* __restrict__ b2, int N) {
  __shared__ float bb[HD];
  int t = threadIdx.x;
  if (t < HD) bb[t] = b2[t];
  __syncthreads();

  int lane = t & 63, c = lane & 31;
  int halfId = (blockIdx.x * 4 + (t >> 6)) * 2 + (lane >> 5);
  int stride = gridDim.x * 8;
  for (int row = halfId; row < N; row += stride) {
    float v = out[(size_t)row * HD + c] + bb[c];
    float m = v;
    for (int off = 16; off; off >>= 1) m = fmaxf(m, __shfl_xor(m, off, 32));
    float ex = __expf(v - m);
    float s = ex;
    for (int off = 16; off; off >>= 1) s += __shfl_xor(s, off, 32);
    out[(size_t)row * HD + c] = v - m - __logf(s);
  }
}

extern "C" void kernel_launch(void* const* d_in, const int* in_sizes, int n_in,
                              void* d_out, int out_size, void* d_ws, size_t ws_size,
                              hipStream_t stream) {
  const float* x  = (const float*)d_in[0];
  const int*   ei = (const int*)d_in[1];
  const float* W1 = (const float*)d_in[2];
  const float* b1 = (const float*)d_in[3];
  const float* W2 = (const float*)d_in[4];
  const float* b2 = (const float*)d_in[5];
  float* out = (float*)d_out;

  const int H   = in_sizes[3];            // 32
  const int Fin = in_sizes[2] / H;        // 512
  const int N   = in_sizes[0] / Fin;      // 100000
  const int E   = in_sizes[1] / 2;        // 3200000
  const int* src = ei;
  const int* dst = ei + E;

  char* wsp = (char*)d_ws;
  size_t off = 0;
  auto nxt = [&](size_t bytes) { char* p = wsp + off; off = (off + bytes + 255) & ~(size_t)255; return p; };
  int*   deg  = (int*)  nxt((size_t)N * 4);
  float* dis  = (float*)nxt((size_t)N * 4);
  float* nrm  = (float*)nxt((size_t)E * 4);
  float* h1   = (float*)nxt((size_t)N * HD * 4);
  float* agg1 = (float*)nxt((size_t)N * HD * 4);
  float* h2   = (float*)nxt((size_t)N * HD * 4);
  (void)ws_size; (void)n_in; (void)out_size;

  int gN = (N + 255) / 256;
  k_deg_init<<<gN, 256, 0, stream>>>(deg, N);
  k_deg_count<<<4096, 256, 0, stream>>>(dst, deg, E);
  k_dis<<<gN, 256, 0, stream>>>(deg, dis, N);
  k_norm<<<4096, 256, 0, stream>>>(src, dst, dis, nrm, E);
  k_mm1<<<512, 256, 0, stream>>>(x, W1, h1, N);
  k_selfinit<<<4096, 256, 0, stream>>>(h1, dis, agg1, N);
  k_scatter<<<4096, 256, 0, stream>>>(src, dst, nrm, h1, agg1, (long long)E * HD);
  k_mm2<<<1024, 256, 0, stream>>>(agg1, b1, W2, dis, h2, out, N);
  k_scatter<<<4096, 256, 0, stream>>>(src, dst, nrm, h2, out, (long long)E * HD);
  k_lsm<<<1024, 256, 0, stream>>>(out, b2, N);
}

// Round 2
// 765.960 us; speedup vs baseline: 1.3640x; 1.3640x over previous
//
#include <hip/hip_runtime.h>
#include <hip/hip_bf16.h>

#define FIN 512
#define HD 32

// ---------------- degree ----------------
__global__ __launch_bounds__(256) void k_deg_init(int* deg, int N) {
  int i = blockIdx.x * 256 + threadIdx.x;
  if (i < N) deg[i] = 1;  // self-loop
}

__global__ __launch_bounds__(256) void k_deg_count(const int* __restrict__ dst, int* deg, int E) {
  int i = blockIdx.x * 256 + threadIdx.x;
  int stride = gridDim.x * 256;
  for (; i < E; i += stride) atomicAdd(&deg[dst[i]], 1);
}

__global__ __launch_bounds__(256) void k_dis(const int* __restrict__ deg, float* dis, int N) {
  int i = blockIdx.x * 256 + threadIdx.x;
  if (i < N) dis[i] = rsqrtf((float)deg[i]);
}

// ---------------- CSR build: prefix-sum of indegree ----------------
__global__ __launch_bounds__(256) void k_bsum(const int* __restrict__ deg, int* bsum, int N) {
  __shared__ int s[256];
  int t = threadIdx.x;
  int i = blockIdx.x * 256 + t;
  s[t] = (i < N) ? deg[i] - 1 : 0;
  __syncthreads();
  for (int off = 128; off; off >>= 1) {
    if (t < off) s[t] += s[t + off];
    __syncthreads();
  }
  if (t == 0) bsum[blockIdx.x] = s[0];
}

__global__ __launch_bounds__(512) void k_sscan(int* bsum, int NB) {  // single block of 512
  __shared__ int s[512];
  int t = threadIdx.x;
  int v = (t < NB) ? bsum[t] : 0;
  s[t] = v;
  __syncthreads();
  for (int off = 1; off < 512; off <<= 1) {
    int a = (t >= off) ? s[t - off] : 0;
    __syncthreads();
    s[t] += a;
    __syncthreads();
  }
  if (t < NB) bsum[t] = s[t] - v;  // exclusive block base
}

__global__ __launch_bounds__(256) void k_offsets(const int* __restrict__ deg, const int* __restrict__ bbase,
                                                 int* __restrict__ offsets, int* __restrict__ cursor, int N) {
  __shared__ int s[256];
  int t = threadIdx.x;
  int i = blockIdx.x * 256 + t;
  int v = (i < N) ? deg[i] - 1 : 0;
  s[t] = v;
  __syncthreads();
  for (int off = 1; off < 256; off <<= 1) {
    int a = (t >= off) ? s[t - off] : 0;
    __syncthreads();
    s[t] += a;
    __syncthreads();
  }
  if (i < N) {
    offsets[i] = bbase[blockIdx.x] + s[t] - v;  // exclusive scan
    cursor[i] = 0;
  }
}

// csr[pos] = (src, norm) bucketed by dst
__global__ __launch_bounds__(256) void k_fill(const int* __restrict__ src, const int* __restrict__ dst,
                                              const float* __restrict__ dis, const int* __restrict__ offsets,
                                              int* __restrict__ cursor, int2* __restrict__ csr, int E) {
  int i = blockIdx.x * 256 + threadIdx.x;
  int stride = gridDim.x * 256;
  for (; i < E; i += stride) {
    int s = src[i], d = dst[i];
    float nr = dis[s] * dis[d];
    int pos = offsets[d] + atomicAdd(&cursor[d], 1);
    csr[pos] = make_int2(s, __float_as_int(nr));
  }
}

// ---------------- mm1: h1 = x @ W1, register-tiled fp32 ----------------
// Block 256 thr = 4 waves; block tile 128 rows x 32 cols; wave tile 32x32;
// thread tile 4x4 (lane: rg=lane>>3 rows, cg=lane&7 cols).
// LDS: W1 full [512][32] (64KB) + x-chunk transposed [64][129] (33KB).
#define KC 64
#define XTP 129
__global__ __launch_bounds__(256) void k_mm1(const float* __restrict__ x, const float* __restrict__ W1,
                                             float* __restrict__ h1, int N) {
  __shared__ float w[FIN * HD];
  __shared__ float xt[KC * XTP];
  const int t = threadIdx.x;

  for (int i = t; i < FIN * HD / 4; i += 256)
    ((float4*)w)[i] = ((const float4*)W1)[i];

  const int wv = t >> 6;
  const int lane = t & 63;
  const int rg = lane >> 3, cg = lane & 7;
  const int rbase = blockIdx.x * 128;

  float acc[4][4];
#pragma unroll
  for (int i = 0; i < 4; ++i)
#pragma unroll
    for (int j = 0; j < 4; ++j) acc[i][j] = 0.f;

  const int srow = t >> 4;        // staging: 16 rows per pass
  const int skq = (t & 15) * 4;   // 4 k's per thread

  for (int kc = 0; kc < FIN; kc += KC) {
    __syncthreads();  // xt readers done (also covers initial w stage)
#pragma unroll
    for (int p = 0; p < 8; ++p) {
      int r = p * 16 + srow;
      int grow = rbase + r;
      float4 v = make_float4(0.f, 0.f, 0.f, 0.f);
      if (grow < N) v = *(const float4*)&x[(size_t)grow * FIN + kc + skq];
      xt[(skq + 0) * XTP + r] = v.x;
      xt[(skq + 1) * XTP + r] = v.y;
      xt[(skq + 2) * XTP + r] = v.z;
      xt[(skq + 3) * XTP + r] = v.w;
    }
    __syncthreads();

#pragma unroll 4
    for (int k = 0; k < KC; ++k) {
      float4 a = *(const float4*)&xt[k * XTP + wv * 32 + rg * 4];
      float4 b = *(const float4*)&w[(kc + k) * HD + cg * 4];
      acc[0][0] += a.x * b.x; acc[0][1] += a.x * b.y; acc[0][2] += a.x * b.z; acc[0][3] += a.x * b.w;
      acc[1][0] += a.y * b.x; acc[1][1] += a.y * b.y; acc[1][2] += a.y * b.z; acc[1][3] += a.y * b.w;
      acc[2][0] += a.z * b.x; acc[2][1] += a.z * b.y; acc[2][2] += a.z * b.z; acc[2][3] += a.z * b.w;
      acc[3][0] += a.w * b.x; acc[3][1] += a.w * b.y; acc[3][2] += a.w * b.z; acc[3][3] += a.w * b.w;
    }
  }

#pragma unroll
  for (int i = 0; i < 4; ++i) {
    int row = rbase + wv * 32 + rg * 4 + i;
    if (row < N)
      *(float4*)&h1[(size_t)row * HD + cg * 4] = make_float4(acc[i][0], acc[i][1], acc[i][2], acc[i][3]);
  }
}

// ---------------- layer1 pull + bias + relu + mm2 -> h2 ----------------
__global__ __launch_bounds__(256) void k_pull1_mm2(const float* __restrict__ h1, const int2* __restrict__ csr,
                                                   const int* __restrict__ offsets, const int* __restrict__ deg,
                                                   const float* __restrict__ dis, const float* __restrict__ b1,
                                                   const float* __restrict__ W2, float* __restrict__ h2, int N) {
  __shared__ float w[HD * HD];
  __shared__ float bb[HD];
  int t = threadIdx.x;
  if (t < HD) bb[t] = b1[t];
  for (int i = t; i < HD * HD; i += 256) w[i] = W2[i];
  __syncthreads();

  int lane = t & 63, c = lane & 31;
  int halfId = (blockIdx.x * 4 + (t >> 6)) * 2 + (lane >> 5);
  int stride = gridDim.x * 8;
  for (int i = halfId; i < N; i += stride) {
    float d = dis[i];
    float acc = h1[(size_t)i * HD + c] * d * d;  // self-loop
    int jb = offsets[i], cnt = deg[i] - 1;
    int j = 0;
    for (; j + 2 <= cnt; j += 2) {
      int2 e0 = csr[jb + j], e1 = csr[jb + j + 1];
      acc += h1[(size_t)e0.x * HD + c] * __int_as_float(e0.y);
      acc += h1[(size_t)e1.x * HD + c] * __int_as_float(e1.y);
    }
    if (j < cnt) {
      int2 e0 = csr[jb + j];
      acc += h1[(size_t)e0.x * HD + c] * __int_as_float(e0.y);
    }
    float tv = fmaxf(acc + bb[c], 0.f);
    float a2 = 0.f;
#pragma unroll
    for (int k = 0; k < HD; ++k) a2 += __shfl(tv, k, 32) * w[k * HD + c];
    h2[(size_t)i * HD + c] = a2;
  }
}

// ---------------- layer2 pull + bias + log_softmax -> out ----------------
__global__ __launch_bounds__(256) void k_pull2_lsm(const float* __restrict__ h2, const int2* __restrict__ csr,
                                                   const int* __restrict__ offsets, const int* __restrict__ deg,
                                                   const float* __restrict__ dis, const float* __restrict__ b2,
                                                   float* __restrict__ out, int N) {
  __shared__ float bb[HD];
  int t = threadIdx.x;
  if (t < HD) bb[t] = b2[t];
  __syncthreads();

  int lane = t & 63, c = lane & 31;
  int halfId = (blockIdx.x * 4 + (t >> 6)) * 2 + (lane >> 5);
  int stride = gridDim.x * 8;
  for (int i = halfId; i < N; i += stride) {
    float d = dis[i];
    float acc = h2[(size_t)i * HD + c] * d * d;  // self-loop
    int jb = offsets[i], cnt = deg[i] - 1;
    int j = 0;
    for (; j + 2 <= cnt; j += 2) {
      int2 e0 = csr[jb + j], e1 = csr[jb + j + 1];
      acc += h2[(size_t)e0.x * HD + c] * __int_as_float(e0.y);
      acc += h2[(size_t)e1.x * HD + c] * __int_as_float(e1.y);
    }
    if (j < cnt) {
      int2 e0 = csr[jb + j];
      acc += h2[(size_t)e0.x * HD + c] * __int_as_float(e0.y);
    }
    float v = acc + bb[c];
    float m = v;
    for (int off = 16; off; off >>= 1) m = fmaxf(m, __shfl_xor(m, off, 32));
    float ex = __expf(v - m);
    float s = ex;
    for (int off = 16; off; off >>= 1) s += __shfl_xor(s, off, 32);
    out[(size_t)i * HD + c] = v - m - __logf(s);
  }
}

extern "C" void kernel_launch(void* const* d_in, const int* in_sizes, int n_in,
                              void* d_out, int out_size, void* d_ws, size_t ws_size,
                              hipStream_t stream) {
  const float* x  = (const float*)d_in[0];
  const int*   ei = (const int*)d_in[1];
  const float* W1 = (const float*)d_in[2];
  const float* b1 = (const float*)d_in[3];
  const float* W2 = (const float*)d_in[4];
  const float* b2 = (const float*)d_in[5];
  float* out = (float*)d_out;

  const int H   = in_sizes[3];            // 32
  const int Fin = in_sizes[2] / H;        // 512
  const int N   = in_sizes[0] / Fin;      // 100000
  const int E   = in_sizes[1] / 2;        // 3200000
  const int* src = ei;
  const int* dst = ei + E;

  char* wsp = (char*)d_ws;
  size_t off = 0;
  auto nxt = [&](size_t bytes) { char* p = wsp + off; off = (off + bytes + 255) & ~(size_t)255; return p; };
  int*   deg     = (int*)  nxt((size_t)N * 4);
  float* dis     = (float*)nxt((size_t)N * 4);
  int*   bsum    = (int*)  nxt(512 * 4);
  int*   offsets = (int*)  nxt((size_t)N * 4);
  int*   cursor  = (int*)  nxt((size_t)N * 4);
  int2*  csr     = (int2*) nxt((size_t)E * 8);
  float* h1      = (float*)nxt((size_t)N * HD * 4);
  float* h2      = (float*)nxt((size_t)N * HD * 4);
  (void)ws_size; (void)n_in; (void)out_size;

  int gN = (N + 255) / 256;   // 391
  int NB = gN;

  k_deg_init<<<gN, 256, 0, stream>>>(deg, N);
  k_deg_count<<<2048, 256, 0, stream>>>(dst, deg, E);
  k_dis<<<gN, 256, 0, stream>>>(deg, dis, N);
  k_bsum<<<NB, 256, 0, stream>>>(deg, bsum, N);
  k_sscan<<<1, 512, 0, stream>>>(bsum, NB);
  k_offsets<<<NB, 256, 0, stream>>>(deg, bsum, offsets, cursor, N);
  k_fill<<<4096, 256, 0, stream>>>(src, dst, dis, offsets, cursor, csr, E);
  k_mm1<<<(N + 127) / 128, 256, 0, stream>>>(x, W1, h1, N);
  k_pull1_mm2<<<2048, 256, 0, stream>>>(h1, csr, offsets, deg, dis, b1, W2, h2, N);
  k_pull2_lsm<<<2048, 256, 0, stream>>>(h2, csr, offsets, deg, dis, b2, out, N);
}

// Round 3
// 583.332 us; speedup vs baseline: 1.7910x; 1.3131x over previous
//
#include <hip/hip_runtime.h>
#include <hip/hip_bf16.h>

#define FIN 512
#define HD 32

// ---------------- degree ----------------
__global__ __launch_bounds__(256) void k_deg_init(int* deg, int N) {
  int i = blockIdx.x * 256 + threadIdx.x;
  if (i < N) deg[i] = 1;  // self-loop
}

__global__ __launch_bounds__(256) void k_deg_count(const int* __restrict__ dst, int* deg, int E) {
  int i = blockIdx.x * 256 + threadIdx.x;
  int stride = gridDim.x * 256;
  for (; i < E; i += stride) atomicAdd(&deg[dst[i]], 1);
}

__global__ __launch_bounds__(256) void k_dis(const int* __restrict__ deg, float* dis, int N) {
  int i = blockIdx.x * 256 + threadIdx.x;
  if (i < N) dis[i] = rsqrtf((float)deg[i]);
}

// ---------------- CSR build: prefix-sum of indegree ----------------
__global__ __launch_bounds__(256) void k_bsum(const int* __restrict__ deg, int* bsum, int N) {
  __shared__ int s[256];
  int t = threadIdx.x;
  int i = blockIdx.x * 256 + t;
  s[t] = (i < N) ? deg[i] - 1 : 0;
  __syncthreads();
  for (int off = 128; off; off >>= 1) {
    if (t < off) s[t] += s[t + off];
    __syncthreads();
  }
  if (t == 0) bsum[blockIdx.x] = s[0];
}

__global__ __launch_bounds__(512) void k_sscan(int* bsum, int NB) {  // single block of 512
  __shared__ int s[512];
  int t = threadIdx.x;
  int v = (t < NB) ? bsum[t] : 0;
  s[t] = v;
  __syncthreads();
  for (int off = 1; off < 512; off <<= 1) {
    int a = (t >= off) ? s[t - off] : 0;
    __syncthreads();
    s[t] += a;
    __syncthreads();
  }
  if (t < NB) bsum[t] = s[t] - v;  // exclusive block base
}

__global__ __launch_bounds__(256) void k_offsets(const int* __restrict__ deg, const int* __restrict__ bbase,
                                                 int* __restrict__ offsets, int* __restrict__ cursor, int N) {
  __shared__ int s[256];
  int t = threadIdx.x;
  int i = blockIdx.x * 256 + t;
  int v = (i < N) ? deg[i] - 1 : 0;
  s[t] = v;
  __syncthreads();
  for (int off = 1; off < 256; off <<= 1) {
    int a = (t >= off) ? s[t - off] : 0;
    __syncthreads();
    s[t] += a;
    __syncthreads();
  }
  if (i < N) {
    offsets[i] = bbase[blockIdx.x] + s[t] - v;  // exclusive scan
    cursor[i] = 0;
  }
}

// csr[pos] = (src, norm) bucketed by dst
__global__ __launch_bounds__(256) void k_fill(const int* __restrict__ src, const int* __restrict__ dst,
                                              const float* __restrict__ dis, const int* __restrict__ offsets,
                                              int* __restrict__ cursor, int2* __restrict__ csr, int E) {
  int i = blockIdx.x * 256 + threadIdx.x;
  int stride = gridDim.x * 256;
  for (; i < E; i += stride) {
    int s = src[i], d = dst[i];
    float nr = dis[s] * dis[d];
    int pos = offsets[d] + atomicAdd(&cursor[d], 1);
    csr[pos] = make_int2(s, __float_as_int(nr));
  }
}

// ---------------- mm1: h1 = x @ W1, register-tiled fp32 ----------------
// Block 256 thr = 4 waves; block tile 128 rows x 32 cols; wave tile 32x32;
// thread tile 4x4 (lane: rg=lane>>3 -> 4-row group, cg=lane&7 -> 4-col group).
// LDS per chunk (KC=32): xs[128][33] fp32 (16.9KB, +1 pad -> conflict-free
// scalar a-reads: bank=(4rg+i+k)%32, 8 banks x 8-lane broadcast) + W chunk
// wc[32][32] (4KB, float4 b-reads span all 32 banks, broadcast x8).
// ~21KB LDS + VGPR<=128 -> 4 blocks/CU = 50% occupancy (was 1 block, 9%).
#define KC 32
#define XSP 33
__global__ __launch_bounds__(256, 4) void k_mm1(const float* __restrict__ x, const float* __restrict__ W1,
                                                float* __restrict__ h1, int N) {
  __shared__ float xs[128 * XSP];
  __shared__ float wc[KC * HD];
  const int t = threadIdx.x;

  const int wv = t >> 6;
  const int lane = t & 63;
  const int rg = lane >> 3, cg = lane & 7;
  const int rbase = blockIdx.x * 128;
  const int arow = wv * 32 + rg * 4;

  const int ss = t & 7;    // k-group for staging (4 floats)
  const int sq = t >> 3;   // row 0..31 per pass

  float acc[4][4];
#pragma unroll
  for (int i = 0; i < 4; ++i)
#pragma unroll
    for (int j = 0; j < 4; ++j) acc[i][j] = 0.f;

  for (int kc = 0; kc < FIN; kc += KC) {
    __syncthreads();  // previous chunk's readers done
    // stage W chunk: 1024 consecutive floats (row-major [32][32])
    ((float4*)wc)[t] = ((const float4*)(W1 + kc * HD))[t];
    // stage x rows [rbase, rbase+128) x k [kc, kc+32), non-transposed
#pragma unroll
    for (int p = 0; p < 4; ++p) {
      int r = p * 32 + sq;
      int grow = rbase + r;
      float4 v = make_float4(0.f, 0.f, 0.f, 0.f);
      if (grow < N) v = *(const float4*)&x[(size_t)grow * FIN + kc + ss * 4];
      float* xr = &xs[r * XSP + ss * 4];
      xr[0] = v.x; xr[1] = v.y; xr[2] = v.z; xr[3] = v.w;
    }
    __syncthreads();

#pragma unroll 8
    for (int k = 0; k < KC; ++k) {
      float4 b = *(const float4*)&wc[k * HD + cg * 4];
      float a0 = xs[(arow + 0) * XSP + k];
      float a1 = xs[(arow + 1) * XSP + k];
      float a2 = xs[(arow + 2) * XSP + k];
      float a3 = xs[(arow + 3) * XSP + k];
      acc[0][0] += a0 * b.x; acc[0][1] += a0 * b.y; acc[0][2] += a0 * b.z; acc[0][3] += a0 * b.w;
      acc[1][0] += a1 * b.x; acc[1][1] += a1 * b.y; acc[1][2] += a1 * b.z; acc[1][3] += a1 * b.w;
      acc[2][0] += a2 * b.x; acc[2][1] += a2 * b.y; acc[2][2] += a2 * b.z; acc[2][3] += a2 * b.w;
      acc[3][0] += a3 * b.x; acc[3][1] += a3 * b.y; acc[3][2] += a3 * b.z; acc[3][3] += a3 * b.w;
    }
  }

#pragma unroll
  for (int i = 0; i < 4; ++i) {
    int row = rbase + arow + i;
    if (row < N)
      *(float4*)&h1[(size_t)row * HD + cg * 4] = make_float4(acc[i][0], acc[i][1], acc[i][2], acc[i][3]);
  }
}

// ---------------- layer1 pull + bias + relu + mm2 -> h2 ----------------
__global__ __launch_bounds__(256) void k_pull1_mm2(const float* __restrict__ h1, const int2* __restrict__ csr,
                                                   const int* __restrict__ offsets, const int* __restrict__ deg,
                                                   const float* __restrict__ dis, const float* __restrict__ b1,
                                                   const float* __restrict__ W2, float* __restrict__ h2, int N) {
  __shared__ float w[HD * HD];
  __shared__ float bb[HD];
  int t = threadIdx.x;
  if (t < HD) bb[t] = b1[t];
  for (int i = t; i < HD * HD; i += 256) w[i] = W2[i];
  __syncthreads();

  int lane = t & 63, c = lane & 31;
  int halfId = (blockIdx.x * 4 + (t >> 6)) * 2 + (lane >> 5);
  int stride = gridDim.x * 8;
  for (int i = halfId; i < N; i += stride) {
    float d = dis[i];
    float acc = h1[(size_t)i * HD + c] * d * d;  // self-loop
    int jb = offsets[i], cnt = deg[i] - 1;
    int j = 0;
    for (; j + 4 <= cnt; j += 4) {  // 4 independent loads + 4 independent gathers (ILP)
      int2 e0 = csr[jb + j], e1 = csr[jb + j + 1], e2 = csr[jb + j + 2], e3 = csr[jb + j + 3];
      float g0 = h1[(size_t)e0.x * HD + c];
      float g1 = h1[(size_t)e1.x * HD + c];
      float g2 = h1[(size_t)e2.x * HD + c];
      float g3 = h1[(size_t)e3.x * HD + c];
      acc += g0 * __int_as_float(e0.y) + g1 * __int_as_float(e1.y)
           + g2 * __int_as_float(e2.y) + g3 * __int_as_float(e3.y);
    }
    for (; j < cnt; ++j) {
      int2 e0 = csr[jb + j];
      acc += h1[(size_t)e0.x * HD + c] * __int_as_float(e0.y);
    }
    float tv = fmaxf(acc + bb[c], 0.f);
    float a2 = 0.f;
#pragma unroll
    for (int k = 0; k < HD; ++k) a2 += __shfl(tv, k, 32) * w[k * HD + c];
    h2[(size_t)i * HD + c] = a2;
  }
}

// ---------------- layer2 pull + bias + log_softmax -> out ----------------
__global__ __launch_bounds__(256) void k_pull2_lsm(const float* __restrict__ h2, const int2* __restrict__ csr,
                                                   const int* __restrict__ offsets, const int* __restrict__ deg,
                                                   const float* __restrict__ dis, const float* __restrict__ b2,
                                                   float* __restrict__ out, int N) {
  __shared__ float bb[HD];
  int t = threadIdx.x;
  if (t < HD) bb[t] = b2[t];
  __syncthreads();

  int lane = t & 63, c = lane & 31;
  int halfId = (blockIdx.x * 4 + (t >> 6)) * 2 + (lane >> 5);
  int stride = gridDim.x * 8;
  for (int i = halfId; i < N; i += stride) {
    float d = dis[i];
    float acc = h2[(size_t)i * HD + c] * d * d;  // self-loop
    int jb = offsets[i], cnt = deg[i] - 1;
    int j = 0;
    for (; j + 4 <= cnt; j += 4) {
      int2 e0 = csr[jb + j], e1 = csr[jb + j + 1], e2 = csr[jb + j + 2], e3 = csr[jb + j + 3];
      float g0 = h2[(size_t)e0.x * HD + c];
      float g1 = h2[(size_t)e1.x * HD + c];
      float g2 = h2[(size_t)e2.x * HD + c];
      float g3 = h2[(size_t)e3.x * HD + c];
      acc += g0 * __int_as_float(e0.y) + g1 * __int_as_float(e1.y)
           + g2 * __int_as_float(e2.y) + g3 * __int_as_float(e3.y);
    }
    for (; j < cnt; ++j) {
      int2 e0 = csr[jb + j];
      acc += h2[(size_t)e0.x * HD + c] * __int_as_float(e0.y);
    }
    float v = acc + bb[c];
    float m = v;
    for (int off = 16; off; off >>= 1) m = fmaxf(m, __shfl_xor(m, off, 32));
    float ex = __expf(v - m);
    float s = ex;
    for (int off = 16; off; off >>= 1) s += __shfl_xor(s, off, 32);
    out[(size_t)i * HD + c] = v - m - __logf(s);
  }
}

extern "C" void kernel_launch(void* const* d_in, const int* in_sizes, int n_in,
                              void* d_out, int out_size, void* d_ws, size_t ws_size,
                              hipStream_t stream) {
  const float* x  = (const float*)d_in[0];
  const int*   ei = (const int*)d_in[1];
  const float* W1 = (const float*)d_in[2];
  const float* b1 = (const float*)d_in[3];
  const float* W2 = (const float*)d_in[4];
  const float* b2 = (const float*)d_in[5];
  float* out = (float*)d_out;

  const int H   = in_sizes[3];            // 32
  const int Fin = in_sizes[2] / H;        // 512
  const int N   = in_sizes[0] / Fin;      // 100000
  const int E   = in_sizes[1] / 2;        // 3200000
  const int* src = ei;
  const int* dst = ei + E;

  char* wsp = (char*)d_ws;
  size_t off = 0;
  auto nxt = [&](size_t bytes) { char* p = wsp + off; off = (off + bytes + 255) & ~(size_t)255; return p; };
  int*   deg     = (int*)  nxt((size_t)N * 4);
  float* dis     = (float*)nxt((size_t)N * 4);
  int*   bsum    = (int*)  nxt(512 * 4);
  int*   offsets = (int*)  nxt((size_t)N * 4);
  int*   cursor  = (int*)  nxt((size_t)N * 4);
  int2*  csr     = (int2*) nxt((size_t)E * 8);
  float* h1      = (float*)nxt((size_t)N * HD * 4);
  float* h2      = (float*)nxt((size_t)N * HD * 4);
  (void)ws_size; (void)n_in; (void)out_size;

  int gN = (N + 255) / 256;   // 391
  int NB = gN;

  k_deg_init<<<gN, 256, 0, stream>>>(deg, N);
  k_deg_count<<<2048, 256, 0, stream>>>(dst, deg, E);
  k_dis<<<gN, 256, 0, stream>>>(deg, dis, N);
  k_bsum<<<NB, 256, 0, stream>>>(deg, bsum, N);
  k_sscan<<<1, 512, 0, stream>>>(bsum, NB);
  k_offsets<<<NB, 256, 0, stream>>>(deg, bsum, offsets, cursor, N);
  k_fill<<<4096, 256, 0, stream>>>(src, dst, dis, offsets, cursor, csr, E);
  k_mm1<<<(N + 127) / 128, 256, 0, stream>>>(x, W1, h1, N);
  k_pull1_mm2<<<2048, 256, 0, stream>>>(h1, csr, offsets, deg, dis, b1, W2, h2, N);
  k_pull2_lsm<<<2048, 256, 0, stream>>>(h2, csr, offsets, deg, dis, b2, out, N);
}